// Round 3
// baseline (320.687 us; speedup 1.0000x reference)
//
#include <hip/hip_runtime.h>
#include <math.h>

// Luong attention fused single-pass, single kernel:
//   scores[b,t] = dec[b] . enc[b,t,:]   (D=256)
//   align = softmax_T(scores); out[b,:] = sum_t align[b,t]*enc[b,t,:]
// Online-softmax -> enc read exactly ONCE (268 MB, ~40us BW floor).
// R3: split-K style fusion — last block per batch (atomic counter) does the
//     combine, eliminating the second kernel launch + full-grid drain.

#define WAVES_PER_BLOCK 4
#define BLOCK 256
#define D 256
#define RBATCH 4

__global__ __launch_bounds__(BLOCK) void attn_fused(
    const float* __restrict__ enc,       // [B,T,D]
    const float* __restrict__ dec,       // [B,D]
    float* __restrict__ ws,              // acc[nblk][D] then ml[nblk][2]
    unsigned int* __restrict__ counters, // [B], zeroed on stream before launch
    float* __restrict__ out,             // [B,D]
    int T, int P, int nblk_total)
{
    const int blk   = blockIdx.x;
    const int b     = blk / P;
    const int chunk = blk % P;
    const int tid   = threadIdx.x;
    const int wave  = tid >> 6;
    const int lane  = tid & 63;

    __shared__ float s_acc[WAVES_PER_BLOCK][D];
    __shared__ float s_m[WAVES_PER_BLOCK];
    __shared__ float s_l[WAVES_PER_BLOCK];
    __shared__ float s_M[WAVES_PER_BLOCK];
    __shared__ float s_L[WAVES_PER_BLOCK];
    __shared__ unsigned s_old;

    const int rows_per_block = T / P;
    const int rows_per_wave  = rows_per_block / WAVES_PER_BLOCK;
    const int t0 = chunk * rows_per_block + wave * rows_per_wave;

    const float* __restrict__ encb = enc + (size_t)b * T * D;
    const float4 dq = *reinterpret_cast<const float4*>(dec + b * D + lane * 4);

    float  m = -INFINITY;
    float  l = 0.0f;
    float4 acc = {0.0f, 0.0f, 0.0f, 0.0f};

    #pragma unroll 2
    for (int r = 0; r < rows_per_wave; r += RBATCH) {
        const float* base = encb + (size_t)(t0 + r) * D + lane * 4;
        const float4 x0 = *reinterpret_cast<const float4*>(base);
        const float4 x1 = *reinterpret_cast<const float4*>(base + D);
        const float4 x2 = *reinterpret_cast<const float4*>(base + 2 * D);
        const float4 x3 = *reinterpret_cast<const float4*>(base + 3 * D);

        float p0 = dq.x * x0.x + dq.y * x0.y + dq.z * x0.z + dq.w * x0.w;
        float p1 = dq.x * x1.x + dq.y * x1.y + dq.z * x1.z + dq.w * x1.w;
        float p2 = dq.x * x2.x + dq.y * x2.y + dq.z * x2.z + dq.w * x2.w;
        float p3 = dq.x * x3.x + dq.y * x3.y + dq.z * x3.z + dq.w * x3.w;

        #pragma unroll
        for (int off = 32; off >= 1; off >>= 1) {
            p0 += __shfl_xor(p0, off, 64);
            p1 += __shfl_xor(p1, off, 64);
            p2 += __shfl_xor(p2, off, 64);
            p3 += __shfl_xor(p3, off, 64);
        }

        const float mn    = fmaxf(fmaxf(fmaxf(p0, p1), fmaxf(p2, p3)), m);
        const float scale = __expf(m - mn);   // 0 when m == -inf
        const float w0 = __expf(p0 - mn);
        const float w1 = __expf(p1 - mn);
        const float w2 = __expf(p2 - mn);
        const float w3 = __expf(p3 - mn);

        acc.x = fmaf(w3, x3.x, fmaf(w2, x2.x, fmaf(w1, x1.x, fmaf(w0, x0.x, acc.x * scale))));
        acc.y = fmaf(w3, x3.y, fmaf(w2, x2.y, fmaf(w1, x1.y, fmaf(w0, x0.y, acc.y * scale))));
        acc.z = fmaf(w3, x3.z, fmaf(w2, x2.z, fmaf(w1, x1.z, fmaf(w0, x0.z, acc.z * scale))));
        acc.w = fmaf(w3, x3.w, fmaf(w2, x2.w, fmaf(w1, x1.w, fmaf(w0, x0.w, acc.w * scale))));
        l = fmaf(l, scale, w0 + w1 + w2 + w3);
        m = mn;
    }

    // ---- intra-block combine: 4 waves -> 1 partial ----
    *reinterpret_cast<float4*>(&s_acc[wave][lane * 4]) = acc;
    if (lane == 0) { s_m[wave] = m; s_l[wave] = l; }
    __syncthreads();

    if (wave == 0) {
        const float M = fmaxf(fmaxf(s_m[0], s_m[1]), fmaxf(s_m[2], s_m[3]));
        float4 a = {0.0f, 0.0f, 0.0f, 0.0f};
        float  L = 0.0f;
        #pragma unroll
        for (int wv = 0; wv < WAVES_PER_BLOCK; ++wv) {
            const float e = __expf(s_m[wv] - M);
            const float4 aw = *reinterpret_cast<const float4*>(&s_acc[wv][lane * 4]);
            a.x += e * aw.x; a.y += e * aw.y; a.z += e * aw.z; a.w += e * aw.w;
            L += e * s_l[wv];
        }
        *reinterpret_cast<float4*>(ws + (size_t)blk * D + lane * 4) = a;
        if (lane == 0) {
            float* ml = ws + (size_t)nblk_total * D;
            ml[blk * 2 + 0] = M;
            ml[blk * 2 + 1] = L;
        }
    }

    // ---- release + arrive ----
    __threadfence();          // device-scope: partials visible before counter bump
    __syncthreads();
    if (tid == 0) s_old = atomicAdd(&counters[b], 1u);
    __syncthreads();
    if (s_old != (unsigned)(P - 1)) return;   // block-uniform

    // ---- last block for batch b: combine P partials ----
    __threadfence();          // acquire: see other blocks' partials
    const float* __restrict__ ml = ws + (size_t)nblk_total * D;
    const int cnt = P / WAVES_PER_BLOCK;
    const int i0  = b * P + wave * cnt;

    float Mw = -INFINITY;
    for (int i = 0; i < cnt; ++i)
        Mw = fmaxf(Mw, ml[(i0 + i) * 2 + 0]);
    if (lane == 0) s_M[wave] = Mw;
    __syncthreads();
    const float M = fmaxf(fmaxf(s_M[0], s_M[1]), fmaxf(s_M[2], s_M[3]));

    float4 a = {0.0f, 0.0f, 0.0f, 0.0f};
    float  L = 0.0f;
    for (int i = 0; i < cnt; ++i) {
        const int pblk = i0 + i;
        const float e  = __expf(ml[pblk * 2 + 0] - M);
        const float4 aw = *reinterpret_cast<const float4*>(ws + (size_t)pblk * D + lane * 4);
        a.x += e * aw.x; a.y += e * aw.y; a.z += e * aw.z; a.w += e * aw.w;
        L += e * ml[pblk * 2 + 1];
    }
    *reinterpret_cast<float4*>(&s_acc[wave][lane * 4]) = a;
    if (lane == 0) s_L[wave] = L;
    __syncthreads();

    if (wave == 0) {
        float4 t = {0.0f, 0.0f, 0.0f, 0.0f};
        float  Lt = 0.0f;
        #pragma unroll
        for (int wv = 0; wv < WAVES_PER_BLOCK; ++wv) {
            const float4 aw = *reinterpret_cast<const float4*>(&s_acc[wv][lane * 4]);
            t.x += aw.x; t.y += aw.y; t.z += aw.z; t.w += aw.w;
            Lt += s_L[wv];
        }
        const float inv = 1.0f / Lt;
        float4 o = {t.x * inv, t.y * inv, t.z * inv, t.w * inv};
        *reinterpret_cast<float4*>(out + b * D + lane * 4) = o;
    }
}

extern "C" void kernel_launch(void* const* d_in, const int* in_sizes, int n_in,
                              void* d_out, int out_size, void* d_ws, size_t ws_size,
                              hipStream_t stream) {
    const float* enc = (const float*)d_in[0];
    const float* dec = (const float*)d_in[1];
    float* out = (float*)d_out;
    float* ws  = (float*)d_ws;

    const int B = in_sizes[1] / D;              // dec is [B, D]
    const int T = in_sizes[0] / in_sizes[1];    // enc is [B, T, D]

    // P chunks per batch; shrink if workspace is small or shape not divisible.
    int P = 64;
    while (P > 1 && ((size_t)B * P * (D + 2) * sizeof(float) + B * sizeof(unsigned) + 256) > ws_size) P >>= 1;
    while (P > 1 && (T % (P * WAVES_PER_BLOCK * RBATCH) != 0)) P >>= 1;

    const int nblk = B * P;
    unsigned* counters = (unsigned*)(ws + (size_t)nblk * D + (size_t)nblk * 2);
    hipMemsetAsync(counters, 0, B * sizeof(unsigned), stream);
    attn_fused<<<nblk, BLOCK, 0, stream>>>(enc, dec, ws, counters, out, T, P, nblk);
}

// Round 4
// 60.049 us; speedup vs baseline: 5.3405x; 5.3405x over previous
//
#include <hip/hip_runtime.h>
#include <math.h>

// Luong attention fused single-pass, two kernels (R3's fused atomic-counter
// version regressed 5x: per-block agent-scope __threadfence() => per-block L2
// writeback maintenance. Never fence per-block.)
//   scores[b,t] = dec[b] . enc[b,t,:]   (D=256)
//   align = softmax_T(scores); out[b,:] = sum_t align[b,t]*enc[b,t,:]
// Online-softmax -> enc read exactly ONCE. R4: kernel2 parallelized 16x
// (B*4 blocks, 4 wave-slices over P, LDS reduce).

#define WAVES_PER_BLOCK 4
#define BLOCK 256
#define D 256
#define RBATCH 4

// Kernel 1: per-(batch,chunk) partial with online softmax.
// ws layout: acc[B*P][256] floats, then interleaved (m,l)[B*P][2].
__global__ __launch_bounds__(BLOCK) void attn_partial(
    const float* __restrict__ enc,   // [B,T,D]
    const float* __restrict__ dec,   // [B,D]
    float* __restrict__ ws,
    int T, int P, int nblk_total)
{
    const int blk   = blockIdx.x;
    const int b     = blk / P;
    const int chunk = blk % P;
    const int tid   = threadIdx.x;
    const int wave  = tid >> 6;
    const int lane  = tid & 63;

    const int rows_per_block = T / P;
    const int rows_per_wave  = rows_per_block / WAVES_PER_BLOCK;
    const int t0 = chunk * rows_per_block + wave * rows_per_wave;

    const float* __restrict__ encb = enc + (size_t)b * T * D;
    const float4 dq = *reinterpret_cast<const float4*>(dec + b * D + lane * 4);

    float  m = -INFINITY;
    float  l = 0.0f;
    float4 acc = {0.0f, 0.0f, 0.0f, 0.0f};

    #pragma unroll 2
    for (int r = 0; r < rows_per_wave; r += RBATCH) {
        const float* base = encb + (size_t)(t0 + r) * D + lane * 4;
        const float4 x0 = *reinterpret_cast<const float4*>(base);
        const float4 x1 = *reinterpret_cast<const float4*>(base + D);
        const float4 x2 = *reinterpret_cast<const float4*>(base + 2 * D);
        const float4 x3 = *reinterpret_cast<const float4*>(base + 3 * D);

        float p0 = dq.x * x0.x + dq.y * x0.y + dq.z * x0.z + dq.w * x0.w;
        float p1 = dq.x * x1.x + dq.y * x1.y + dq.z * x1.z + dq.w * x1.w;
        float p2 = dq.x * x2.x + dq.y * x2.y + dq.z * x2.z + dq.w * x2.w;
        float p3 = dq.x * x3.x + dq.y * x3.y + dq.z * x3.z + dq.w * x3.w;

        #pragma unroll
        for (int off = 32; off >= 1; off >>= 1) {
            p0 += __shfl_xor(p0, off, 64);
            p1 += __shfl_xor(p1, off, 64);
            p2 += __shfl_xor(p2, off, 64);
            p3 += __shfl_xor(p3, off, 64);
        }

        const float mn    = fmaxf(fmaxf(fmaxf(p0, p1), fmaxf(p2, p3)), m);
        const float scale = __expf(m - mn);   // 0 when m == -inf
        const float w0 = __expf(p0 - mn);
        const float w1 = __expf(p1 - mn);
        const float w2 = __expf(p2 - mn);
        const float w3 = __expf(p3 - mn);

        acc.x = fmaf(w3, x3.x, fmaf(w2, x2.x, fmaf(w1, x1.x, fmaf(w0, x0.x, acc.x * scale))));
        acc.y = fmaf(w3, x3.y, fmaf(w2, x2.y, fmaf(w1, x1.y, fmaf(w0, x0.y, acc.y * scale))));
        acc.z = fmaf(w3, x3.z, fmaf(w2, x2.z, fmaf(w1, x1.z, fmaf(w0, x0.z, acc.z * scale))));
        acc.w = fmaf(w3, x3.w, fmaf(w2, x2.w, fmaf(w1, x1.w, fmaf(w0, x0.w, acc.w * scale))));
        l = fmaf(l, scale, w0 + w1 + w2 + w3);
        m = mn;
    }

    // combine the 4 waves' partials in LDS -> one partial per block
    __shared__ float s_acc[WAVES_PER_BLOCK][D];
    __shared__ float s_m[WAVES_PER_BLOCK];
    __shared__ float s_l[WAVES_PER_BLOCK];

    *reinterpret_cast<float4*>(&s_acc[wave][lane * 4]) = acc;
    if (lane == 0) { s_m[wave] = m; s_l[wave] = l; }
    __syncthreads();

    if (wave == 0) {
        const float M = fmaxf(fmaxf(s_m[0], s_m[1]), fmaxf(s_m[2], s_m[3]));
        float4 a = {0.0f, 0.0f, 0.0f, 0.0f};
        float  L = 0.0f;
        #pragma unroll
        for (int wv = 0; wv < WAVES_PER_BLOCK; ++wv) {
            const float e = __expf(s_m[wv] - M);
            const float4 aw = *reinterpret_cast<const float4*>(&s_acc[wv][lane * 4]);
            a.x += e * aw.x; a.y += e * aw.y; a.z += e * aw.z; a.w += e * aw.w;
            L += e * s_l[wv];
        }
        *reinterpret_cast<float4*>(ws + (size_t)blk * D + lane * 4) = a;
        if (lane == 0) {
            float* ml = ws + (size_t)nblk_total * D;
            ml[blk * 2 + 0] = M;
            ml[blk * 2 + 1] = L;
        }
    }
}

// Kernel 2: combine P partials per batch, normalize, write out.
// grid = B*4 blocks; block handles one 64-column quarter.
// threads: col = tid&63, slice = tid>>6; slice strides the P loop.
__global__ __launch_bounds__(BLOCK) void attn_combine(
    const float* __restrict__ ws,
    float* __restrict__ out,
    int P, int nblk_total)
{
    const int b     = blockIdx.x >> 2;
    const int cq    = blockIdx.x & 3;
    const int tid   = threadIdx.x;
    const int col   = cq * 64 + (tid & 63);
    const int slice = tid >> 6;

    const float* __restrict__ ml = ws + (size_t)nblk_total * D;

    // global max over this batch's P partials (small, cached)
    float M = -INFINITY;
    for (int i = 0; i < P; ++i)
        M = fmaxf(M, ml[(b * P + i) * 2 + 0]);

    float a = 0.0f, L = 0.0f;
    for (int i = slice; i < P; i += 4) {
        const int pblk = b * P + i;
        const float e  = __expf(ml[pblk * 2 + 0] - M);
        a = fmaf(e, ws[(size_t)pblk * D + col], a);
        L = fmaf(e, ml[pblk * 2 + 1], L);
    }

    __shared__ float s_a[4][64];
    __shared__ float s_L[4];
    s_a[slice][tid & 63] = a;
    if ((tid & 63) == 0) s_L[slice] = L;
    __syncthreads();

    if (slice == 0) {
        const float at = s_a[0][tid] + s_a[1][tid] + s_a[2][tid] + s_a[3][tid];
        const float Lt = s_L[0] + s_L[1] + s_L[2] + s_L[3];
        out[b * D + col] = at / Lt;
    }
}

extern "C" void kernel_launch(void* const* d_in, const int* in_sizes, int n_in,
                              void* d_out, int out_size, void* d_ws, size_t ws_size,
                              hipStream_t stream) {
    const float* enc = (const float*)d_in[0];
    const float* dec = (const float*)d_in[1];
    float* out = (float*)d_out;
    float* ws  = (float*)d_ws;

    const int B = in_sizes[1] / D;              // dec is [B, D]
    const int T = in_sizes[0] / in_sizes[1];    // enc is [B, T, D]

    // P chunks per batch; shrink if workspace is small or shape not divisible.
    int P = 64;
    while (P > 1 && ((size_t)B * P * (D + 2) * sizeof(float)) > ws_size) P >>= 1;
    while (P > 1 && (T % (P * WAVES_PER_BLOCK * RBATCH) != 0)) P >>= 1;

    const int nblk = B * P;
    attn_partial<<<nblk, BLOCK, 0, stream>>>(enc, dec, ws, T, P, nblk);
    attn_combine<<<B * 4, BLOCK, 0, stream>>>(ws, out, P, nblk);
}